// Round 9
// baseline (87.524 us; speedup 1.0000x reference)
//
#include <hip/hip_runtime.h>
#include <math.h>

#define BB 256
#define NN 1024
#define KK 64
#define EE 128
#define TM 128     // rows per block (8 waves x 16 rows)

typedef _Float16 half8 __attribute__((ext_vector_type(8)));
typedef float f32x4 __attribute__((ext_vector_type(4)));

// swizzled half-index for a [128][128] f16 LDS tile: XOR 16B-slot bits by row&7
__device__ __forceinline__ int swz(int row, int halfcol) {
    return (row * EE + halfcol) ^ ((row & 7) << 3);
}

// async global->LDS 16B: linear LDS dest, per-lane global src
__device__ __forceinline__ void gload_lds16(const void* g, void* l) {
    __builtin_amdgcn_global_load_lds(
        (const __attribute__((address_space(1))) unsigned int*)g,
        (__attribute__((address_space(3))) unsigned int*)l, 16, 0, 0);
}

// ---------------- prep: Mt (f16), bias, t_abc (float4, revolution units); W2 -> f16 ----------------
// C = adj @ (w_real + i w_imag); M = [[Cr, Ci], [-Ci, Cr]]; x_pre = [cos|sin] @ M + [br|bi]
// Mt[f][j] = M[j][f]  (MFMA B-frags = contiguous rows)
__global__ __launch_bounds__(256) void prep_kernel(
    const float* __restrict__ recip,
    const int* __restrict__ space_group,
    const float* __restrict__ abc,
    const float* __restrict__ graphs,
    const float* __restrict__ w_real,
    const float* __restrict__ w_imag,
    const float* __restrict__ b_real,
    const float* __restrict__ b_imag,
    const float* __restrict__ W2,
    _Float16* __restrict__ Mt,      // B*E*E
    float* __restrict__ bbout,      // B*E
    float* __restrict__ tabcP,      // B*K*4
    _Float16* __restrict__ W2h)     // E*E
{
    const int b = blockIdx.x;
    const int t = threadIdx.x;
    const int sg = space_group[b] - 1;

    if (b < EE * EE / 256) {
        const int idx = b * 256 + t;
        W2h[idx] = (_Float16)W2[idx];
    }

    __shared__ float adjL[KK * KK];
    __shared__ float wrL[KK * KK];
    __shared__ float wiL[KK * KK];

    const float* adjG = graphs + (size_t)sg * KK * KK;
    const float* wrG  = w_real + (size_t)sg * KK * KK;
    const float* wiG  = w_imag + (size_t)sg * KK * KK;
    for (int idx = t; idx < KK * KK; idx += 256) {
        adjL[idx] = adjG[idx];
        wrL[idx]  = wrG[idx];
        wiL[idx]  = wiG[idx];
    }
    __syncthreads();

    const int i  = t >> 2;
    const int f0 = (t & 3) * 16;
    float cr[16], ci[16];
#pragma unroll
    for (int c = 0; c < 16; ++c) { cr[c] = 0.f; ci[c] = 0.f; }
    for (int k = 0; k < KK; ++k) {
        const float a = adjL[i * KK + k];
#pragma unroll
        for (int c = 0; c < 16; ++c) {
            cr[c] += a * wrL[k * KK + f0 + c];
            ci[c] += a * wiL[k * KK + f0 + c];
        }
    }
    _Float16* Mb = Mt + (size_t)b * EE * EE;
#pragma unroll
    for (int c = 0; c < 16; ++c) {
        const int f = f0 + c;
        Mb[f * EE + i]             = (_Float16)cr[c];
        Mb[f * EE + KK + i]        = (_Float16)(-ci[c]);
        Mb[(KK + f) * EE + i]      = (_Float16)ci[c];
        Mb[(KK + f) * EE + KK + i] = (_Float16)cr[c];
    }
    if (t < EE) {
        bbout[b * EE + t] = (t < KK) ? b_real[sg * KK + t] : b_imag[sg * KK + (t - KK)];
    }
    if (t < KK) {
        const float a0 = abc[t * 3 + 0], a1 = abc[t * 3 + 1], a2 = abc[t * 3 + 2];
        const float* R = recip + b * 9;
        float4 v;
        v.x = a0 * R[0] + a1 * R[1] + a2 * R[2];
        v.y = a0 * R[3] + a1 * R[4] + a2 * R[5];
        v.z = a0 * R[6] + a1 * R[7] + a2 * R[8];
        v.w = 0.f;
        *(float4*)&tabcP[((size_t)b * KK + t) * 4] = v;
    }
}

// ---- common helpers ----
__device__ __forceinline__ void block_map(int d, int& b, int& n0) {
    // XCD swizzle: all 8 blocks of a batch on one XCD
    const int j = d >> 3;
    b  = (d & 7) * 32 + (j >> 3);
    n0 = (j & 7) * TM;
}

__device__ __forceinline__ void make_afrag(const float* tp, float px, float py, float pz,
                                           int kg, half8 afrag[4]) {
#pragma unroll
    for (int mq = 0; mq < 2; ++mq) {
        _Float16 cb[8], sb[8];
#pragma unroll
        for (int jj = 0; jj < 8; ++jj) {
            const int k = mq * 32 + kg * 8 + jj;
            const float4 tv = *(const float4*)&tp[k * 4];
            const float rev = px * tv.x + py * tv.y + pz * tv.z;  // phase / 2pi
            const float fr  = __builtin_amdgcn_fractf(rev);
            sb[jj] = (_Float16)__builtin_amdgcn_sinf(fr);   // sin(2pi*fr)
            cb[jj] = (_Float16)__builtin_amdgcn_cosf(fr);   // cos(2pi*fr)
        }
        afrag[mq]     = *(half8*)cb;   // cos -> k-chunks 0,1
        afrag[mq + 2] = *(half8*)sb;   // sin -> k-chunks 2,3
    }
}

// ---------------- kernel A: sincos -> mm1 -> silu -> X (f16 row-major, global) ----------------
__global__ __launch_bounds__(512) void mm1_kernel(
    const float* __restrict__ pos,      // B*N*3
    const _Float16* __restrict__ Mt,    // B*E*E f16
    const float* __restrict__ bball,    // B*E
    const float* __restrict__ tabcP,    // B*K*4 (revolutions)
    _Float16* __restrict__ Xg)          // B*N*E f16
{
    int b, n0;
    block_map(blockIdx.x, b, n0);
    const int t  = threadIdx.x;
    const int w    = t >> 6;
    const int lane = t & 63;
    const int ln15 = lane & 15;
    const int kg   = lane >> 4;

    __shared__ __align__(16) _Float16 Bt[EE * EE];  // 32KB

    // ---- issue async Mt staging (linear LDS dest, inverse-swizzled source) ----
    {
        const char* srcM = (const char*)(Mt + (size_t)b * EE * EE);
#pragma unroll
        for (int i = 0; i < 4; ++i) {
            const int c16 = t + i * 512;
            const int row = c16 >> 4;
            const int sl  = c16 & 15;
            const int g   = row * 16 + (sl ^ (row & 7));
            gload_lds16(srcM + g * 16, (char*)Bt + c16 * 16);
        }
    }

    // ---- per-lane A-fragments (hides Mt load) ----
    const int grow = n0 + w * 16 + ln15;
    const float* pr = pos + ((size_t)b * NN + grow) * 3;
    const float px = pr[0], py = pr[1], pz = pr[2];
    half8 afrag[4];
    make_afrag(tabcP + (size_t)b * KK * 4, px, py, pz, kg, afrag);
    __syncthreads();   // drains vmcnt(0): Bt(Mt) ready

    // ---- matmul1 ----
    f32x4 acc[8];
#pragma unroll
    for (int nt = 0; nt < 8; ++nt) {
        const int n = nt * 16 + ln15;
        f32x4 a = {0.f, 0.f, 0.f, 0.f};
#pragma unroll
        for (int kc = 0; kc < 4; ++kc) {
            const half8 bf = *(const half8*)&Bt[swz(n, kc * 32 + kg * 8)];
            a = __builtin_amdgcn_mfma_f32_16x16x32_f16(afrag[kc], bf, a, 0, 0, 0);
        }
        acc[nt] = a;
    }

    // ---- bias + silu -> X global (f16 row-major; L2 merges the 32B segments) ----
#pragma unroll
    for (int nt = 0; nt < 8; ++nt) {
        const int col = nt * 16 + ln15;
        const float bbv = bball[b * EE + col];
#pragma unroll
        for (int r2 = 0; r2 < 4; ++r2) {
            const float v = acc[nt][r2] + bbv;
            const int rr = w * 16 + kg * 4 + r2;
            Xg[((size_t)b * NN + n0 + rr) * EE + col] =
                (_Float16)(v / (1.f + __expf(-v)));
        }
    }
}

// ---------------- kernel B: X -> mm2 -> LayerNorm -> out ----------------
__global__ __launch_bounds__(512) void mm2_kernel(
    const _Float16* __restrict__ Xg,    // B*N*E f16
    const _Float16* __restrict__ W2h,   // E*E f16
    const float* __restrict__ b2,       // E
    const float* __restrict__ gamma,    // E
    const float* __restrict__ beta,     // E
    float* __restrict__ out)            // B*N*E
{
    int b, n0;
    block_map(blockIdx.x, b, n0);
    const int t  = threadIdx.x;
    const int w    = t >> 6;
    const int lane = t & 63;
    const int ln15 = lane & 15;
    const int kg   = lane >> 4;

    __shared__ __align__(16) _Float16 Bt[EE * EE];  // 32KB

    // ---- prefetch this lane's A-frags from X (4 independent dwordx4 loads) ----
    const int grow = n0 + w * 16 + ln15;
    const _Float16* xrow = Xg + ((size_t)b * NN + grow) * EE;
    half8 a2[4];
#pragma unroll
    for (int kc = 0; kc < 4; ++kc)
        a2[kc] = *(const half8*)&xrow[kc * 32 + kg * 8];

    // ---- issue async W2 staging ----
    {
        const char* srcW = (const char*)W2h;
#pragma unroll
        for (int i = 0; i < 4; ++i) {
            const int c16 = t + i * 512;
            const int row = c16 >> 4;
            const int sl  = c16 & 15;
            const int g   = row * 16 + (sl ^ (row & 7));
            gload_lds16(srcW + g * 16, (char*)Bt + c16 * 16);
        }
    }
    __syncthreads();   // drains vmcnt(0): Bt(W2) ready (and a2 loads done)

    // ---- matmul2 ----
    f32x4 acc2[8];
#pragma unroll
    for (int nt = 0; nt < 8; ++nt) {
        const int n = nt * 16 + ln15;
        f32x4 a = {0.f, 0.f, 0.f, 0.f};
#pragma unroll
        for (int kc = 0; kc < 4; ++kc) {
            const half8 bf = *(const half8*)&Bt[swz(n, kc * 32 + kg * 8)];
            a = __builtin_amdgcn_mfma_f32_16x16x32_f16(a2[kc], bf, a, 0, 0, 0);
        }
        acc2[nt] = a;
    }

    // ---- + b2, LayerNorm over E (16-lane shfl), store ----
    float s[4] = {0.f, 0.f, 0.f, 0.f}, q[4] = {0.f, 0.f, 0.f, 0.f};
#pragma unroll
    for (int nt = 0; nt < 8; ++nt) {
        const int col = nt * 16 + ln15;
        const float b2v = b2[col];
#pragma unroll
        for (int r2 = 0; r2 < 4; ++r2) {
            const float v = acc2[nt][r2] + b2v;
            acc2[nt][r2] = v;
            s[r2] += v;
            q[r2] += v * v;
        }
    }
#pragma unroll
    for (int m = 1; m < 16; m <<= 1) {
#pragma unroll
        for (int r2 = 0; r2 < 4; ++r2) {
            s[r2] += __shfl_xor(s[r2], m);
            q[r2] += __shfl_xor(q[r2], m);
        }
    }
    const float inv = 1.f / EE;
    float mu[4], rs[4];
#pragma unroll
    for (int r2 = 0; r2 < 4; ++r2) {
        mu[r2] = s[r2] * inv;
        rs[r2] = rsqrtf(fmaxf(q[r2] * inv - mu[r2] * mu[r2], 0.f) + 1e-5f);
    }
#pragma unroll
    for (int nt = 0; nt < 8; ++nt) {
        const int col = nt * 16 + ln15;
        const float g  = gamma[col];
        const float be = beta[col];
#pragma unroll
        for (int r2 = 0; r2 < 4; ++r2) {
            const int rr = w * 16 + kg * 4 + r2;
            out[((size_t)b * NN + n0 + rr) * EE + col] =
                (acc2[nt][r2] - mu[r2]) * rs[r2] * g + be;
        }
    }
}

// ---------------- fallback fused kernel (R7 structure, HW sincos) ----------------
__global__ __launch_bounds__(512, 4) void fused_kernel(
    const float* __restrict__ pos,
    const _Float16* __restrict__ Mt,
    const float* __restrict__ bball,
    const float* __restrict__ tabcP,
    const _Float16* __restrict__ W2h,
    const float* __restrict__ b2,
    const float* __restrict__ gamma,
    const float* __restrict__ beta,
    float* __restrict__ out)
{
    int b, n0;
    block_map(blockIdx.x, b, n0);
    const int t  = threadIdx.x;
    const int w    = t >> 6;
    const int lane = t & 63;
    const int ln15 = lane & 15;
    const int kg   = lane >> 4;

    __shared__ __align__(16) _Float16 arena[2 * EE * EE];
    _Float16* Bt = arena;
    _Float16* X  = arena + EE * EE;

    {
        const char* srcM = (const char*)(Mt + (size_t)b * EE * EE);
#pragma unroll
        for (int i = 0; i < 4; ++i) {
            const int c16 = t + i * 512;
            const int row = c16 >> 4;
            const int sl  = c16 & 15;
            const int g   = row * 16 + (sl ^ (row & 7));
            gload_lds16(srcM + g * 16, (char*)Bt + c16 * 16);
        }
    }
    const int grow = n0 + w * 16 + ln15;
    const float* pr = pos + ((size_t)b * NN + grow) * 3;
    const float px = pr[0], py = pr[1], pz = pr[2];
    half8 afrag[4];
    make_afrag(tabcP + (size_t)b * KK * 4, px, py, pz, kg, afrag);
    __syncthreads();

    f32x4 acc[8];
#pragma unroll
    for (int nt = 0; nt < 8; ++nt) {
        const int n = nt * 16 + ln15;
        f32x4 a = {0.f, 0.f, 0.f, 0.f};
#pragma unroll
        for (int kc = 0; kc < 4; ++kc) {
            const half8 bf = *(const half8*)&Bt[swz(n, kc * 32 + kg * 8)];
            a = __builtin_amdgcn_mfma_f32_16x16x32_f16(afrag[kc], bf, a, 0, 0, 0);
        }
        acc[nt] = a;
    }
    __syncthreads();

    {
        const char* srcW = (const char*)W2h;
#pragma unroll
        for (int i = 0; i < 4; ++i) {
            const int c16 = t + i * 512;
            const int row = c16 >> 4;
            const int sl  = c16 & 15;
            const int g   = row * 16 + (sl ^ (row & 7));
            gload_lds16(srcW + g * 16, (char*)Bt + c16 * 16);
        }
    }
#pragma unroll
    for (int nt = 0; nt < 8; ++nt) {
        const int col = nt * 16 + ln15;
        const float bbv = bball[b * EE + col];
#pragma unroll
        for (int r2 = 0; r2 < 4; ++r2) {
            const float v = acc[nt][r2] + bbv;
            const int rr = w * 16 + kg * 4 + r2;
            X[swz(rr, col)] = (_Float16)(v / (1.f + __expf(-v)));
        }
    }
    const int arow = w * 16 + ln15;
    half8 a2[4];
#pragma unroll
    for (int kc = 0; kc < 4; ++kc)
        a2[kc] = *(const half8*)&X[swz(arow, kc * 32 + kg * 8)];
    __syncthreads();

    f32x4 acc2[8];
#pragma unroll
    for (int nt = 0; nt < 8; ++nt) {
        const int n = nt * 16 + ln15;
        f32x4 a = {0.f, 0.f, 0.f, 0.f};
#pragma unroll
        for (int kc = 0; kc < 4; ++kc) {
            const half8 bf = *(const half8*)&Bt[swz(n, kc * 32 + kg * 8)];
            a = __builtin_amdgcn_mfma_f32_16x16x32_f16(a2[kc], bf, a, 0, 0, 0);
        }
        acc2[nt] = a;
    }

    float s[4] = {0.f, 0.f, 0.f, 0.f}, q[4] = {0.f, 0.f, 0.f, 0.f};
#pragma unroll
    for (int nt = 0; nt < 8; ++nt) {
        const int col = nt * 16 + ln15;
        const float b2v = b2[col];
#pragma unroll
        for (int r2 = 0; r2 < 4; ++r2) {
            const float v = acc2[nt][r2] + b2v;
            acc2[nt][r2] = v;
            s[r2] += v;
            q[r2] += v * v;
        }
    }
#pragma unroll
    for (int m = 1; m < 16; m <<= 1) {
#pragma unroll
        for (int r2 = 0; r2 < 4; ++r2) {
            s[r2] += __shfl_xor(s[r2], m);
            q[r2] += __shfl_xor(q[r2], m);
        }
    }
    const float inv = 1.f / EE;
    float mu[4], rs[4];
#pragma unroll
    for (int r2 = 0; r2 < 4; ++r2) {
        mu[r2] = s[r2] * inv;
        rs[r2] = rsqrtf(fmaxf(q[r2] * inv - mu[r2] * mu[r2], 0.f) + 1e-5f);
    }
#pragma unroll
    for (int nt = 0; nt < 8; ++nt) {
        const int col = nt * 16 + ln15;
        const float g  = gamma[col];
        const float be = beta[col];
#pragma unroll
        for (int r2 = 0; r2 < 4; ++r2) {
            const int rr = w * 16 + kg * 4 + r2;
            out[((size_t)b * NN + n0 + rr) * EE + col] =
                (acc2[nt][r2] - mu[r2]) * rs[r2] * g + be;
        }
    }
}

extern "C" void kernel_launch(void* const* d_in, const int* in_sizes, int n_in,
                              void* d_out, int out_size, void* d_ws, size_t ws_size,
                              hipStream_t stream) {
    const float* pos    = (const float*)d_in[0];
    const float* recip  = (const float*)d_in[1];
    const int*   sgp    = (const int*)d_in[2];
    const float* abc    = (const float*)d_in[3];
    const float* graphs = (const float*)d_in[4];
    const float* wr     = (const float*)d_in[5];
    const float* wi     = (const float*)d_in[6];
    const float* br     = (const float*)d_in[7];
    const float* bi     = (const float*)d_in[8];
    const float* W2     = (const float*)d_in[9];
    const float* b2     = (const float*)d_in[10];
    const float* gm     = (const float*)d_in[11];
    const float* bt     = (const float*)d_in[12];
    float* out = (float*)d_out;

    char* ws = (char*)d_ws;
    _Float16* Mt    = (_Float16*)ws;                                     // 8 MiB
    char* p = ws + (size_t)BB * EE * EE * 2;
    _Float16* W2h   = (_Float16*)p;            p += EE * EE * 2;         // 32 KiB
    float*    bball = (float*)p;               p += (size_t)BB * EE * 4; // 128 KiB
    float*    tabcP = (float*)p;               p += (size_t)BB * KK * 16;// 256 KiB
    _Float16* Xg    = (_Float16*)p;                                      // 64 MiB
    const size_t need = (size_t)(p - ws) + (size_t)BB * NN * EE * 2;

    hipLaunchKernelGGL(prep_kernel, dim3(BB), dim3(256), 0, stream,
                       recip, sgp, abc, graphs, wr, wi, br, bi, W2, Mt, bball, tabcP, W2h);
    if (ws_size >= need) {
        hipLaunchKernelGGL(mm1_kernel, dim3(BB * NN / TM), dim3(512), 0, stream,
                           pos, Mt, bball, tabcP, Xg);
        hipLaunchKernelGGL(mm2_kernel, dim3(BB * NN / TM), dim3(512), 0, stream,
                           Xg, W2h, b2, gm, bt, out);
    } else {
        hipLaunchKernelGGL(fused_kernel, dim3(BB * NN / TM), dim3(512), 0, stream,
                           pos, Mt, bball, tabcP, W2h, b2, gm, bt, out);
    }
}

// Round 10
// 67.699 us; speedup vs baseline: 1.2928x; 1.2928x over previous
//
#include <hip/hip_runtime.h>
#include <math.h>

#define BB 256
#define NN 1024
#define KK 64
#define EE 128
#define TM 64      // rows per block (4 waves x 16 rows)

typedef _Float16 half8 __attribute__((ext_vector_type(8)));
typedef float f32x4 __attribute__((ext_vector_type(4)));

// swizzled half-index for a [rows][128] f16 LDS tile: XOR 16B-slot bits by row&7
__device__ __forceinline__ int swz(int row, int halfcol) {
    return (row * EE + halfcol) ^ ((row & 7) << 3);
}

// async global->LDS 16B: linear LDS dest, per-lane global src
__device__ __forceinline__ void gload_lds16(const void* g, void* l) {
    __builtin_amdgcn_global_load_lds(
        (const __attribute__((address_space(1))) unsigned int*)g,
        (__attribute__((address_space(3))) unsigned int*)l, 16, 0, 0);
}

// ---------------- prep: Mt (f16), bias, t_abc (float4, revolution units); W2 -> f16 ----------------
// C = adj @ (w_real + i w_imag); M = [[Cr, Ci], [-Ci, Cr]]; x_pre = [cos|sin] @ M + [br|bi]
// Mt[f][j] = M[j][f]  (MFMA B-frags = contiguous rows)
__global__ __launch_bounds__(256) void prep_kernel(
    const float* __restrict__ recip,
    const int* __restrict__ space_group,
    const float* __restrict__ abc,
    const float* __restrict__ graphs,
    const float* __restrict__ w_real,
    const float* __restrict__ w_imag,
    const float* __restrict__ b_real,
    const float* __restrict__ b_imag,
    const float* __restrict__ W2,
    _Float16* __restrict__ Mt,      // B*E*E
    float* __restrict__ bbout,      // B*E
    float* __restrict__ tabcP,      // B*K*4 (revolutions)
    _Float16* __restrict__ W2h)     // E*E
{
    const int b = blockIdx.x;
    const int t = threadIdx.x;
    const int sg = space_group[b] - 1;

    if (b < EE * EE / 256) {
        const int idx = b * 256 + t;
        W2h[idx] = (_Float16)W2[idx];
    }

    __shared__ float adjL[KK * KK];
    __shared__ float wrL[KK * KK];
    __shared__ float wiL[KK * KK];

    const float* adjG = graphs + (size_t)sg * KK * KK;
    const float* wrG  = w_real + (size_t)sg * KK * KK;
    const float* wiG  = w_imag + (size_t)sg * KK * KK;
    for (int idx = t; idx < KK * KK; idx += 256) {
        adjL[idx] = adjG[idx];
        wrL[idx]  = wrG[idx];
        wiL[idx]  = wiG[idx];
    }
    __syncthreads();

    const int i  = t >> 2;
    const int f0 = (t & 3) * 16;
    float cr[16], ci[16];
#pragma unroll
    for (int c = 0; c < 16; ++c) { cr[c] = 0.f; ci[c] = 0.f; }
    for (int k = 0; k < KK; ++k) {
        const float a = adjL[i * KK + k];
#pragma unroll
        for (int c = 0; c < 16; ++c) {
            cr[c] += a * wrL[k * KK + f0 + c];
            ci[c] += a * wiL[k * KK + f0 + c];
        }
    }
    _Float16* Mb = Mt + (size_t)b * EE * EE;
#pragma unroll
    for (int c = 0; c < 16; ++c) {
        const int f = f0 + c;
        Mb[f * EE + i]             = (_Float16)cr[c];
        Mb[f * EE + KK + i]        = (_Float16)(-ci[c]);
        Mb[(KK + f) * EE + i]      = (_Float16)ci[c];
        Mb[(KK + f) * EE + KK + i] = (_Float16)cr[c];
    }
    if (t < EE) {
        bbout[b * EE + t] = (t < KK) ? b_real[sg * KK + t] : b_imag[sg * KK + (t - KK)];
    }
    if (t < KK) {
        const float a0 = abc[t * 3 + 0], a1 = abc[t * 3 + 1], a2 = abc[t * 3 + 2];
        const float* R = recip + b * 9;
        float4 v;
        v.x = a0 * R[0] + a1 * R[1] + a2 * R[2];
        v.y = a0 * R[3] + a1 * R[4] + a2 * R[5];
        v.z = a0 * R[6] + a1 * R[7] + a2 * R[8];
        v.w = 0.f;
        *(float4*)&tabcP[((size_t)b * KK + t) * 4] = v;
    }
}

// ---------------- main fused MFMA kernel (R4 structure + chain-fat cuts) ----------------
__global__ __launch_bounds__(256) void main_kernel(
    const float* __restrict__ pos,      // B*N*3
    const _Float16* __restrict__ Mt,    // B*E*E f16
    const float* __restrict__ bball,    // B*E
    const float* __restrict__ tabcP,    // B*K*4 (revolutions)
    const _Float16* __restrict__ W2h,   // E*E f16
    const float* __restrict__ b2,       // E
    const float* __restrict__ gamma,    // E
    const float* __restrict__ beta,     // E
    float* __restrict__ out)            // B*N*E
{
    const int d = blockIdx.x;           // 0..4095
    // XCD swizzle: all 16 blocks of a batch on one XCD (Mt HBM-fetched once per batch)
    const int j  = d >> 3;              // 0..511 within XCD
    const int b  = (d & 7) * 32 + (j >> 4);
    const int n0 = (j & 15) * TM;
    const int t  = threadIdx.x;
    const int w    = t >> 6;            // wave 0..3 -> rows w*16..w*16+15
    const int lane = t & 63;
    const int ln15 = lane & 15;
    const int kg   = lane >> 4;         // 0..3

    __shared__ __align__(16) _Float16 Bt[EE * EE];  // 32KB: Mt, later W2
    __shared__ __align__(16) _Float16 X[TM * EE];   // 16KB: silu output

    // ---- issue async Mt staging: LDS linear, global source inverse-swizzled ----
    {
        const char* srcM = (const char*)(Mt + (size_t)b * EE * EE);
#pragma unroll
        for (int i = 0; i < 8; ++i) {
            const int c16 = t + i * 256;          // 0..2047
            const int row = c16 >> 4;
            const int sl  = c16 & 15;
            const int g   = row * 16 + (sl ^ (row & 7));
            gload_lds16(srcM + g * 16, (char*)Bt + c16 * 16);
        }
    }

    // ---- per-lane A-fragments: HW sin/cos in revolutions (hides Mt load) ----
    // A layout: row=lane&15 (lane's row = w*16+ln15), k=(lane>>4)*8+j
    const int grow = n0 + w * 16 + ln15;
    const float* pr = pos + ((size_t)b * NN + grow) * 3;
    const float px = pr[0], py = pr[1], pz = pr[2];
    const float* tp = tabcP + (size_t)b * KK * 4;

    half8 afrag[4];
#pragma unroll
    for (int mq = 0; mq < 2; ++mq) {
        _Float16 cb[8], sb[8];
#pragma unroll
        for (int jj = 0; jj < 8; ++jj) {
            const int k = mq * 32 + kg * 8 + jj;
            const float4 tv = *(const float4*)&tp[k * 4];
            const float rev = px * tv.x + py * tv.y + pz * tv.z;  // phase / 2pi
            const float fr  = __builtin_amdgcn_fractf(rev);
            sb[jj] = (_Float16)__builtin_amdgcn_sinf(fr);   // sin(2pi*fr)
            cb[jj] = (_Float16)__builtin_amdgcn_cosf(fr);   // cos(2pi*fr)
        }
        afrag[mq]     = *(half8*)cb;   // cos -> k-chunks 0,1
        afrag[mq + 2] = *(half8*)sb;   // sin -> k-chunks 2,3
    }
    __syncthreads();   // drains vmcnt(0): Bt(Mt) ready

    // ---- matmul1: x_pre = A @ M ----
    f32x4 acc[8];
#pragma unroll
    for (int nt = 0; nt < 8; ++nt) {
        const int n = nt * 16 + ln15;
        f32x4 a = {0.f, 0.f, 0.f, 0.f};
#pragma unroll
        for (int kc = 0; kc < 4; ++kc) {
            const half8 bf = *(const half8*)&Bt[swz(n, kc * 32 + kg * 8)];
            a = __builtin_amdgcn_mfma_f32_16x16x32_f16(afrag[kc], bf, a, 0, 0, 0);
        }
        acc[nt] = a;
    }
    __syncthreads();   // all waves done reading Bt(Mt) -> safe to overwrite

    // ---- issue async W2 staging NOW; silu below hides its L2 latency ----
    {
        const char* srcW = (const char*)W2h;
#pragma unroll
        for (int i = 0; i < 8; ++i) {
            const int c16 = t + i * 256;
            const int row = c16 >> 4;
            const int sl  = c16 & 15;
            const int g   = row * 16 + (sl ^ (row & 7));
            gload_lds16(srcW + g * 16, (char*)Bt + c16 * 16);
        }
    }

    // ---- bias + silu -> X via v_rcp (D layout: row=(lane>>4)*4+r2, col=lane&15) ----
#pragma unroll
    for (int nt = 0; nt < 8; ++nt) {
        const int col = nt * 16 + ln15;
        const float bbv = bball[b * EE + col];
#pragma unroll
        for (int r2 = 0; r2 < 4; ++r2) {
            const float v = acc[nt][r2] + bbv;
            const int rr = w * 16 + kg * 4 + r2;
            X[swz(rr, col)] = (_Float16)(v * __builtin_amdgcn_rcpf(1.f + __expf(-v)));
        }
    }

    // ---- A-frags for matmul2 from X (own wave's rows; in-wave LDS ordering) ----
    const int arow = w * 16 + ln15;
    half8 a2[4];
#pragma unroll
    for (int kc = 0; kc < 4; ++kc)
        a2[kc] = *(const half8*)&X[swz(arow, kc * 32 + kg * 8)];
    __syncthreads();   // drains vmcnt(0): Bt(W2) ready

    // ---- matmul2: y = X @ W2^T ----
    f32x4 acc2[8];
#pragma unroll
    for (int nt = 0; nt < 8; ++nt) {
        const int n = nt * 16 + ln15;
        f32x4 a = {0.f, 0.f, 0.f, 0.f};
#pragma unroll
        for (int kc = 0; kc < 4; ++kc) {
            const half8 bf = *(const half8*)&Bt[swz(n, kc * 32 + kg * 8)];
            a = __builtin_amdgcn_mfma_f32_16x16x32_f16(a2[kc], bf, a, 0, 0, 0);
        }
        acc2[nt] = a;
    }

    // ---- + b2, LayerNorm over E (16-lane shfl, v_rsq), store ----
    float s[4] = {0.f, 0.f, 0.f, 0.f}, q[4] = {0.f, 0.f, 0.f, 0.f};
#pragma unroll
    for (int nt = 0; nt < 8; ++nt) {
        const int col = nt * 16 + ln15;
        const float b2v = b2[col];
#pragma unroll
        for (int r2 = 0; r2 < 4; ++r2) {
            const float v = acc2[nt][r2] + b2v;
            acc2[nt][r2] = v;
            s[r2] += v;
            q[r2] += v * v;
        }
    }
#pragma unroll
    for (int m = 1; m < 16; m <<= 1) {
#pragma unroll
        for (int r2 = 0; r2 < 4; ++r2) {
            s[r2] += __shfl_xor(s[r2], m);
            q[r2] += __shfl_xor(q[r2], m);
        }
    }
    const float inv = 1.f / EE;
    float mu[4], rs[4];
#pragma unroll
    for (int r2 = 0; r2 < 4; ++r2) {
        mu[r2] = s[r2] * inv;
        rs[r2] = __builtin_amdgcn_rsqf(fmaxf(q[r2] * inv - mu[r2] * mu[r2], 0.f) + 1e-5f);
    }
#pragma unroll
    for (int nt = 0; nt < 8; ++nt) {
        const int col = nt * 16 + ln15;
        const float g  = gamma[col];
        const float be = beta[col];
#pragma unroll
        for (int r2 = 0; r2 < 4; ++r2) {
            const int rr = w * 16 + kg * 4 + r2;
            out[((size_t)b * NN + n0 + rr) * EE + col] =
                (acc2[nt][r2] - mu[r2]) * rs[r2] * g + be;
        }
    }
}

extern "C" void kernel_launch(void* const* d_in, const int* in_sizes, int n_in,
                              void* d_out, int out_size, void* d_ws, size_t ws_size,
                              hipStream_t stream) {
    const float* pos    = (const float*)d_in[0];
    const float* recip  = (const float*)d_in[1];
    const int*   sgp    = (const int*)d_in[2];
    const float* abc    = (const float*)d_in[3];
    const float* graphs = (const float*)d_in[4];
    const float* wr     = (const float*)d_in[5];
    const float* wi     = (const float*)d_in[6];
    const float* br     = (const float*)d_in[7];
    const float* bi     = (const float*)d_in[8];
    const float* W2     = (const float*)d_in[9];
    const float* b2     = (const float*)d_in[10];
    const float* gm     = (const float*)d_in[11];
    const float* bt     = (const float*)d_in[12];
    float* out = (float*)d_out;

    char* ws = (char*)d_ws;
    _Float16* Mt    = (_Float16*)ws;                                     // 8 MiB
    char* p = ws + (size_t)BB * EE * EE * 2;
    _Float16* W2h   = (_Float16*)p;            p += EE * EE * 2;         // 32 KiB
    float*    bball = (float*)p;               p += (size_t)BB * EE * 4; // 128 KiB
    float*    tabcP = (float*)p;                                         // 256 KiB

    hipLaunchKernelGGL(prep_kernel, dim3(BB), dim3(256), 0, stream,
                       recip, sgp, abc, graphs, wr, wi, br, bi, W2, Mt, bball, tabcP, W2h);
    hipLaunchKernelGGL(main_kernel, dim3(BB * NN / TM), dim3(256), 0, stream,
                       pos, Mt, bball, tabcP, W2h, b2, gm, bt, out);
}

// Round 12
// 66.571 us; speedup vs baseline: 1.3148x; 1.0169x over previous
//
#include <hip/hip_runtime.h>
#include <math.h>

#define BB 256
#define NN 1024
#define KK 64
#define EE 128
#define TM 64      // rows per block (4 waves x 16 rows)

typedef _Float16 half8 __attribute__((ext_vector_type(8)));
typedef __fp16 fp16x2 __attribute__((ext_vector_type(2)));
typedef float f32x4 __attribute__((ext_vector_type(4)));

// swizzled half-index for a [rows][128] f16 LDS tile: XOR 16B-slot bits by row&7
__device__ __forceinline__ int swz(int row, int halfcol) {
    return (row * EE + halfcol) ^ ((row & 7) << 3);
}

// async global->LDS 16B: linear LDS dest, per-lane global src
__device__ __forceinline__ void gload_lds16(const void* g, void* l) {
    __builtin_amdgcn_global_load_lds(
        (const __attribute__((address_space(1))) unsigned int*)g,
        (__attribute__((address_space(3))) unsigned int*)l, 16, 0, 0);
}

// ---------------- prep: Mt (f16), bias, t_abc (float4, revolution units); W2 -> f16 ----------------
// C = adj @ (w_real + i w_imag); M = [[Cr, Ci], [-Ci, Cr]]; x_pre = [cos|sin] @ M + [br|bi]
// Mt[f][j] = M[j][f]  (MFMA fragments = contiguous rows)
__global__ __launch_bounds__(256) void prep_kernel(
    const float* __restrict__ recip,
    const int* __restrict__ space_group,
    const float* __restrict__ abc,
    const float* __restrict__ graphs,
    const float* __restrict__ w_real,
    const float* __restrict__ w_imag,
    const float* __restrict__ b_real,
    const float* __restrict__ b_imag,
    const float* __restrict__ W2,
    _Float16* __restrict__ Mt,      // B*E*E
    float* __restrict__ bbout,      // B*E
    float* __restrict__ tabcP,      // B*K*4 (revolutions)
    _Float16* __restrict__ W2h)     // E*E
{
    const int b = blockIdx.x;
    const int t = threadIdx.x;
    const int sg = space_group[b] - 1;

    if (b < EE * EE / 256) {
        const int idx = b * 256 + t;
        W2h[idx] = (_Float16)W2[idx];
    }

    __shared__ float adjL[KK * KK];
    __shared__ float wrL[KK * KK];
    __shared__ float wiL[KK * KK];

    const float* adjG = graphs + (size_t)sg * KK * KK;
    const float* wrG  = w_real + (size_t)sg * KK * KK;
    const float* wiG  = w_imag + (size_t)sg * KK * KK;
    for (int idx = t; idx < KK * KK; idx += 256) {
        adjL[idx] = adjG[idx];
        wrL[idx]  = wrG[idx];
        wiL[idx]  = wiG[idx];
    }
    __syncthreads();

    const int i  = t >> 2;
    const int f0 = (t & 3) * 16;
    float cr[16], ci[16];
#pragma unroll
    for (int c = 0; c < 16; ++c) { cr[c] = 0.f; ci[c] = 0.f; }
    for (int k = 0; k < KK; ++k) {
        const float a = adjL[i * KK + k];
#pragma unroll
        for (int c = 0; c < 16; ++c) {
            cr[c] += a * wrL[k * KK + f0 + c];
            ci[c] += a * wiL[k * KK + f0 + c];
        }
    }
    _Float16* Mb = Mt + (size_t)b * EE * EE;
#pragma unroll
    for (int c = 0; c < 16; ++c) {
        const int f = f0 + c;
        Mb[f * EE + i]             = (_Float16)cr[c];
        Mb[f * EE + KK + i]        = (_Float16)(-ci[c]);
        Mb[(KK + f) * EE + i]      = (_Float16)ci[c];
        Mb[(KK + f) * EE + KK + i] = (_Float16)cr[c];
    }
    if (t < EE) {
        bbout[b * EE + t] = (t < KK) ? b_real[sg * KK + t] : b_imag[sg * KK + (t - KK)];
    }
    if (t < KK) {
        const float a0 = abc[t * 3 + 0], a1 = abc[t * 3 + 1], a2 = abc[t * 3 + 2];
        const float* R = recip + b * 9;
        float4 v;
        v.x = a0 * R[0] + a1 * R[1] + a2 * R[2];
        v.y = a0 * R[3] + a1 * R[4] + a2 * R[5];
        v.z = a0 * R[6] + a1 * R[7] + a2 * R[8];
        v.w = 0.f;
        *(float4*)&tabcP[((size_t)b * KK + t) * 4] = v;
    }
}

// ---------------- main fused MFMA kernel (transposed mm1 -> vectorized X path) ----------------
__global__ __launch_bounds__(256) void main_kernel(
    const float* __restrict__ pos,      // B*N*3
    const _Float16* __restrict__ Mt,    // B*E*E f16
    const float* __restrict__ bball,    // B*E
    const float* __restrict__ tabcP,    // B*K*4 (revolutions)
    const _Float16* __restrict__ W2h,   // E*E f16
    const float* __restrict__ b2,       // E
    const float* __restrict__ gamma,    // E
    const float* __restrict__ beta,     // E
    float* __restrict__ out)            // B*N*E
{
    const int d = blockIdx.x;           // 0..4095
    // XCD swizzle: all 16 blocks of a batch on one XCD (Mt HBM-fetched once per batch)
    const int j  = d >> 3;              // 0..511 within XCD
    const int b  = (d & 7) * 32 + (j >> 4);
    const int n0 = (j & 15) * TM;
    const int t  = threadIdx.x;
    const int w    = t >> 6;            // wave 0..3 -> rows w*16..w*16+15
    const int lane = t & 63;
    const int ln15 = lane & 15;
    const int kg   = lane >> 4;         // 0..3

    __shared__ __align__(16) _Float16 Bt[EE * EE];  // 32KB: Mt, later W2
    __shared__ __align__(16) _Float16 X[TM * EE];   // 16KB: silu output

    // ---- issue async Mt staging: LDS linear, global source inverse-swizzled ----
    {
        const char* srcM = (const char*)(Mt + (size_t)b * EE * EE);
#pragma unroll
        for (int i = 0; i < 8; ++i) {
            const int c16 = t + i * 256;          // 0..2047
            const int row = c16 >> 4;
            const int sl  = c16 & 15;
            const int g   = row * 16 + (sl ^ (row & 7));
            gload_lds16(srcM + g * 16, (char*)Bt + c16 * 16);
        }
    }

    // ---- per-lane sincos fragments: HW sin/cos in revolutions (hides Mt load) ----
    // frag layout (A or B role): row/col = lane&15, k = (lane>>4)*8+j
    const int grow = n0 + w * 16 + ln15;
    const float* pr = pos + ((size_t)b * NN + grow) * 3;
    const float px = pr[0], py = pr[1], pz = pr[2];
    const float* tp = tabcP + (size_t)b * KK * 4;

    half8 afrag[4];
#pragma unroll
    for (int mq = 0; mq < 2; ++mq) {
        _Float16 cb[8], sb[8];
#pragma unroll
        for (int jj = 0; jj < 8; ++jj) {
            const int k = mq * 32 + kg * 8 + jj;
            const float4 tv = *(const float4*)&tp[k * 4];
            const float rev = px * tv.x + py * tv.y + pz * tv.z;  // phase / 2pi
            const float fr  = __builtin_amdgcn_fractf(rev);
            sb[jj] = (_Float16)__builtin_amdgcn_sinf(fr);   // sin(2pi*fr)
            cb[jj] = (_Float16)__builtin_amdgcn_cosf(fr);   // cos(2pi*fr)
        }
        afrag[mq]     = *(half8*)cb;   // cos -> k-chunks 0,1
        afrag[mq + 2] = *(half8*)sb;   // sin -> k-chunks 2,3
    }
    __syncthreads();   // drains vmcnt(0): Bt(Mt) ready

    // ---- matmul1 TRANSPOSED: D_nt = Mt_tile (A-op) x sincos (B-op) = (X tile)^T ----
    // lane (ln15,kg) reg r2 holds X[row=ln15... wait: D row=(lane>>4)*4+r2 maps to COL here]
    // With swapped operands: D[i][j], i = Mt row (n), j = sincos row (x-row).
    // D layout: col j = lane&15 -> x-row = w*16? NO: j = ln15 is the sincos fragment row
    // within this wave's 16 rows; D row i = kg*4+r2 + nt*16 = the output feature.
    // So lane (ln15,kg) reg r2 holds X[row = w*16 + ln15][col = nt*16 + kg*4 + r2]... 
    // (x-row ln15 is THIS wave's row group since afrag came from row w*16+ln15)
    f32x4 acc[8];
#pragma unroll
    for (int nt = 0; nt < 8; ++nt) {
        const int n = nt * 16 + ln15;
        f32x4 a = {0.f, 0.f, 0.f, 0.f};
#pragma unroll
        for (int kc = 0; kc < 4; ++kc) {
            const half8 bf = *(const half8*)&Bt[swz(n, kc * 32 + kg * 8)];
            a = __builtin_amdgcn_mfma_f32_16x16x32_f16(bf, afrag[kc], a, 0, 0, 0);
        }
        acc[nt] = a;
    }
    __syncthreads();   // all waves done reading Bt(Mt) -> safe to overwrite

    // ---- issue async W2 staging NOW; silu below hides its L2 latency ----
    {
        const char* srcW = (const char*)W2h;
#pragma unroll
        for (int i = 0; i < 8; ++i) {
            const int c16 = t + i * 256;
            const int row = c16 >> 4;
            const int sl  = c16 & 15;
            const int g   = row * 16 + (sl ^ (row & 7));
            gload_lds16(srcW + g * 16, (char*)Bt + c16 * 16);
        }
    }

    // ---- bias + silu -> X: float4 bias, pkrtz pairs, ONE 8B write per nt ----
    {
        const int xrow = w * 16 + ln15;            // this lane's X row
        const float* bbp = bball + b * EE;
#pragma unroll
        for (int nt = 0; nt < 8; ++nt) {
            const int cb0 = nt * 16 + kg * 4;      // 4 consecutive cols
            const float4 bb4 = *(const float4*)&bbp[cb0];
            float sv[4];
            sv[0] = acc[nt][0] + bb4.x;
            sv[1] = acc[nt][1] + bb4.y;
            sv[2] = acc[nt][2] + bb4.z;
            sv[3] = acc[nt][3] + bb4.w;
#pragma unroll
            for (int r2 = 0; r2 < 4; ++r2)
                sv[r2] = sv[r2] * __builtin_amdgcn_rcpf(1.f + __expf(-sv[r2]));
            const fp16x2 p0 = __builtin_amdgcn_cvt_pkrtz(sv[0], sv[1]);
            const fp16x2 p1 = __builtin_amdgcn_cvt_pkrtz(sv[2], sv[3]);
            uint2 u;
            u.x = __builtin_bit_cast(unsigned int, p0);
            u.y = __builtin_bit_cast(unsigned int, p1);
            *(uint2*)&X[swz(xrow, cb0)] = u;       // 8B store; swizzle keeps 8B alignment
        }
    }

    // ---- A-frags for matmul2 from X (own wave's rows; in-wave LDS ordering) ----
    const int arow = w * 16 + ln15;
    half8 a2[4];
#pragma unroll
    for (int kc = 0; kc < 4; ++kc)
        a2[kc] = *(const half8*)&X[swz(arow, kc * 32 + kg * 8)];
    __syncthreads();   // drains vmcnt(0): Bt(W2) ready

    // ---- matmul2: y = X @ W2^T (normal orientation; D rows = n) ----
    f32x4 acc2[8];
#pragma unroll
    for (int nt = 0; nt < 8; ++nt) {
        const int n = nt * 16 + ln15;
        f32x4 a = {0.f, 0.f, 0.f, 0.f};
#pragma unroll
        for (int kc = 0; kc < 4; ++kc) {
            const half8 bf = *(const half8*)&Bt[swz(n, kc * 32 + kg * 8)];
            a = __builtin_amdgcn_mfma_f32_16x16x32_f16(a2[kc], bf, a, 0, 0, 0);
        }
        acc2[nt] = a;
    }

    // ---- + b2, LayerNorm over E (16-lane shfl, v_rsq), store ----
    float s[4] = {0.f, 0.f, 0.f, 0.f}, q[4] = {0.f, 0.f, 0.f, 0.f};
#pragma unroll
    for (int nt = 0; nt < 8; ++nt) {
        const int col = nt * 16 + ln15;
        const float b2v = b2[col];
#pragma unroll
        for (int r2 = 0; r2 < 4; ++r2) {
            const float v = acc2[nt][r2] + b2v;
            acc2[nt][r2] = v;
            s[r2] += v;
            q[r2] += v * v;
        }
    }
#pragma unroll
    for (int m = 1; m < 16; m <<= 1) {
#pragma unroll
        for (int r2 = 0; r2 < 4; ++r2) {
            s[r2] += __shfl_xor(s[r2], m);
            q[r2] += __shfl_xor(q[r2], m);
        }
    }
    const float inv = 1.f / EE;
    float mu[4], rs[4];
#pragma unroll
    for (int r2 = 0; r2 < 4; ++r2) {
        mu[r2] = s[r2] * inv;
        rs[r2] = __builtin_amdgcn_rsqf(fmaxf(q[r2] * inv - mu[r2] * mu[r2], 0.f) + 1e-5f);
    }
#pragma unroll
    for (int nt = 0; nt < 8; ++nt) {
        const int col = nt * 16 + ln15;
        const float g  = gamma[col];
        const float be = beta[col];
#pragma unroll
        for (int r2 = 0; r2 < 4; ++r2) {
            const int rr = w * 16 + kg * 4 + r2;
            out[((size_t)b * NN + n0 + rr) * EE + col] =
                (acc2[nt][r2] - mu[r2]) * rs[r2] * g + be;
        }
    }
}

extern "C" void kernel_launch(void* const* d_in, const int* in_sizes, int n_in,
                              void* d_out, int out_size, void* d_ws, size_t ws_size,
                              hipStream_t stream) {
    const float* pos    = (const float*)d_in[0];
    const float* recip  = (const float*)d_in[1];
    const int*   sgp    = (const int*)d_in[2];
    const float* abc    = (const float*)d_in[3];
    const float* graphs = (const float*)d_in[4];
    const float* wr     = (const float*)d_in[5];
    const float* wi     = (const float*)d_in[6];
    const float* br     = (const float*)d_in[7];
    const float* bi     = (const float*)d_in[8];
    const float* W2     = (const float*)d_in[9];
    const float* b2     = (const float*)d_in[10];
    const float* gm     = (const float*)d_in[11];
    const float* bt     = (const float*)d_in[12];
    float* out = (float*)d_out;

    char* ws = (char*)d_ws;
    _Float16* Mt    = (_Float16*)ws;                                     // 8 MiB
    char* p = ws + (size_t)BB * EE * EE * 2;
    _Float16* W2h   = (_Float16*)p;            p += EE * EE * 2;         // 32 KiB
    float*    bball = (float*)p;               p += (size_t)BB * EE * 4; // 128 KiB
    float*    tabcP = (float*)p;                                         // 256 KiB

    hipLaunchKernelGGL(prep_kernel, dim3(BB), dim3(256), 0, stream,
                       recip, sgp, abc, graphs, wr, wi, br, bi, W2, Mt, bball, tabcP, W2h);
    hipLaunchKernelGGL(main_kernel, dim3(BB * NN / TM), dim3(256), 0, stream,
                       pos, Mt, bball, tabcP, W2h, b2, gm, bt, out);
}